// Round 1
// baseline (292.091 us; speedup 1.0000x reference)
//
#include <hip/hip_runtime.h>
#include <hip/hip_bf16.h>
#include <math.h>

#define B_SZ    1024
#define DI      2560
#define DS      16
#define DR      160
#define NPROJ   192   // DR + DS + DS

typedef __bf16 bf16x8 __attribute__((ext_vector_type(8)));
typedef float  f32x4  __attribute__((ext_vector_type(4)));

// ---------------- kernel 0: fp32 -> bf16 conversions + negA = -exp(A_log) ----
__global__ void __launch_bounds__(256) convert_kernel(
    const float* __restrict__ x, const float* __restrict__ Wdl,
    const float* __restrict__ WB, const float* __restrict__ WC,
    const float* __restrict__ Wdt, const float* __restrict__ A_log,
    __bf16* __restrict__ xb, __bf16* __restrict__ wcat,
    __bf16* __restrict__ wdtb, float* __restrict__ negA) {
  int i = blockIdx.x * 256 + threadIdx.x;
  const int NX   = B_SZ * DI;   // 2621440
  const int NWDL = DR * DI;     // 409600
  const int NWB  = DS * DI;     // 40960
  const int NWDT = DI * DR;     // 409600
  const int NA   = DI * DS;     // 40960
  if (i < NX)   { xb[i] = (__bf16)x[i]; return; }
  i -= NX;
  if (i < NWDL) { wcat[i] = (__bf16)Wdl[i]; return; }
  i -= NWDL;
  if (i < NWB)  { wcat[NWDL + i] = (__bf16)WB[i]; return; }
  i -= NWB;
  if (i < NWB)  { wcat[NWDL + NWB + i] = (__bf16)WC[i]; return; }
  i -= NWB;
  if (i < NWDT) { wdtb[i] = (__bf16)Wdt[i]; return; }
  i -= NWDT;
  if (i < NA)   { negA[i] = -__expf(A_log[i]); }
}

// ---------------- kernel 1: proj GEMM  C[1024,192] = xb . wcat^T -------------
// per-wave 16x16 tile, K=2560 in 80 MFMA steps, no LDS (L2-bound, ~3.6us)
__global__ void __launch_bounds__(256) proj_kernel(
    const __bf16* __restrict__ xb, const __bf16* __restrict__ wcat,
    __bf16* __restrict__ dtlow, float* __restrict__ Bt, float* __restrict__ Ct) {
  int gw    = blockIdx.x * 4 + (threadIdx.x >> 6);   // 768 wave-tiles
  int lane  = threadIdx.x & 63;
  int mtile = gw & 63;       // 64 m-tiles of 16
  int ntile = gw >> 6;       // 12 n-tiles of 16
  int b0 = mtile * 16, n0 = ntile * 16;
  int m = lane & 15, quad = lane >> 4;
  const __bf16* ap = xb   + (size_t)(b0 + m) * DI + quad * 8;
  const __bf16* bp = wcat + (size_t)(n0 + m) * DI + quad * 8;  // n-index = lane&15
  f32x4 acc = {0.f, 0.f, 0.f, 0.f};
  for (int k0 = 0; k0 < DI; k0 += 32) {
    bf16x8 a = *(const bf16x8*)(ap + k0);
    bf16x8 b = *(const bf16x8*)(bp + k0);
    acc = __builtin_amdgcn_mfma_f32_16x16x32_bf16(a, b, acc, 0, 0, 0);
  }
  // D layout: col = lane&15 (n), row = quad*4 + r (m)   [verified mapping]
  int nn = n0 + m;
#pragma unroll
  for (int r = 0; r < 4; ++r) {
    int bb = b0 + quad * 4 + r;
    float v = acc[r];
    if (nn < DR)            dtlow[bb * DR + nn] = (__bf16)v;
    else if (nn < DR + DS)  Bt[bb * DS + (nn - DR)] = v;
    else                    Ct[bb * DS + (nn - DR - DS)] = v;
  }
}

// ---------------- kernel 2: dt GEMM + softplus -------------------------------
// C[1024,2560] = dtlow . Wdt^T, K=160 in 5 MFMA steps
__global__ void __launch_bounds__(256) dt_kernel(
    const __bf16* __restrict__ dtlow, const __bf16* __restrict__ wdtb,
    const float* __restrict__ b_dt, float* __restrict__ dt) {
  int gw    = blockIdx.x * 4 + (threadIdx.x >> 6);   // 10240 wave-tiles
  int lane  = threadIdx.x & 63;
  int mtile = gw & 63;       // 64 m-tiles
  int ntile = gw >> 6;       // 160 n-tiles
  int b0 = mtile * 16, d0 = ntile * 16;
  int m = lane & 15, quad = lane >> 4;
  const __bf16* ap = dtlow + (size_t)(b0 + m) * DR + quad * 8;
  const __bf16* bp = wdtb  + (size_t)(d0 + m) * DR + quad * 8;
  f32x4 acc = {0.f, 0.f, 0.f, 0.f};
#pragma unroll
  for (int k0 = 0; k0 < DR; k0 += 32) {
    bf16x8 a = *(const bf16x8*)(ap + k0);
    bf16x8 b = *(const bf16x8*)(bp + k0);
    acc = __builtin_amdgcn_mfma_f32_16x16x32_bf16(a, b, acc, 0, 0, 0);
  }
  int dd = d0 + m;
  float bias = b_dt[dd];
#pragma unroll
  for (int r = 0; r < 4; ++r) {
    int bb = b0 + quad * 4 + r;
    float z = acc[r] + bias;
    float sp = (z > 20.f) ? z : log1pf(__expf(z));
    dt[(size_t)bb * DI + dd] = sp;
  }
}

// ---------------- kernel 3: memory-bound h pass ------------------------------
// y[b,d] = sum_n (exp(dt*A[d,n])*h[b,d,n] + dt*Bt[b,n]*x[b,d]) * Ct[b,n] + D[d]*x
__global__ void __launch_bounds__(256) ssm_kernel(
    const float* __restrict__ x, const float* __restrict__ h,
    const float* __restrict__ dt, const float* __restrict__ negA,
    const float* __restrict__ Bt, const float* __restrict__ Ct,
    const float* __restrict__ Dp, float* __restrict__ y) {
  int e = blockIdx.x * 256 + threadIdx.x;   // e = b*DI + d, 2.62M total
  int b = e / DI;
  int d = e - b * DI;
  float dtv = dt[e];
  float xv  = x[e];
  float dtl = dtv * 1.44269504f;   // dt * log2(e), for exp2
  float dxv = dtv * xv;
  const float4* h4 = (const float4*)(h    + (size_t)e * DS);
  const float4* a4 = (const float4*)(negA + (size_t)d * DS);
  const float4* b4 = (const float4*)(Bt   + (size_t)b * DS);
  const float4* c4 = (const float4*)(Ct   + (size_t)b * DS);
  float acc = 0.f;
#pragma unroll
  for (int j = 0; j < 4; ++j) {
    float4 hv = h4[j], av = a4[j], bv = b4[j], cv = c4[j];
    acc += (exp2f(av.x * dtl) * hv.x + bv.x * dxv) * cv.x;
    acc += (exp2f(av.y * dtl) * hv.y + bv.y * dxv) * cv.y;
    acc += (exp2f(av.z * dtl) * hv.z + bv.z * dxv) * cv.z;
    acc += (exp2f(av.w * dtl) * hv.w + bv.w * dxv) * cv.w;
  }
  y[e] = acc + Dp[d] * xv;
}

extern "C" void kernel_launch(void* const* d_in, const int* in_sizes, int n_in,
                              void* d_out, int out_size, void* d_ws, size_t ws_size,
                              hipStream_t stream) {
  const float* x     = (const float*)d_in[0];
  const float* h     = (const float*)d_in[1];
  const float* Wdl   = (const float*)d_in[2];
  const float* Wdt   = (const float*)d_in[3];
  const float* b_dt  = (const float*)d_in[4];
  const float* WB    = (const float*)d_in[5];
  const float* WC    = (const float*)d_in[6];
  const float* A_log = (const float*)d_in[7];
  const float* Dp    = (const float*)d_in[8];
  float* y = (float*)d_out;

  // workspace layout (all offsets 256B-aligned)
  char* ws = (char*)d_ws;
  __bf16* xb    = (__bf16*)(ws);                       // 5,242,880 B
  __bf16* wcat  = (__bf16*)(ws + 5242880);             //   983,040 B
  __bf16* wdtb  = (__bf16*)(ws + 6225920);             //   819,200 B
  float*  negA  = (float*) (ws + 7045120);             //   163,840 B
  __bf16* dtlow = (__bf16*)(ws + 7208960);             //   327,680 B
  float*  Bt    = (float*) (ws + 7536640);             //    65,536 B
  float*  Ct    = (float*) (ws + 7602176);             //    65,536 B
  float*  dt    = (float*) (ws + 7667712);             // 10,485,760 B -> total 18,153,472
  if (ws_size < 18153472) return;  // workspace too small (would corrupt)

  // k0: conversions. 3,563,520 elems -> 13920 blocks
  convert_kernel<<<13920, 256, 0, stream>>>(x, Wdl, WB, WC, Wdt, A_log,
                                            xb, wcat, wdtb, negA);
  // k1: 768 wave-tiles / 4 waves per block
  proj_kernel<<<192, 256, 0, stream>>>(xb, wcat, dtlow, Bt, Ct);
  // k2: 10240 wave-tiles / 4 waves per block
  dt_kernel<<<2560, 256, 0, stream>>>(dtlow, wdtb, b_dt, dt);
  // k3: 2,621,440 elems
  ssm_kernel<<<10240, 256, 0, stream>>>(x, h, dt, negA, Bt, Ct, Dp, y);
}